// Round 7
// baseline (510.892 us; speedup 1.0000x reference)
//
#include <hip/hip_runtime.h>
#include <math.h>

// Pipeline: bin points by (y,x,z,w>>1) cell (2M buckets) -> process in cell
// order. Main kernel: 256 threads / 256 points per block, ZERO block LDS,
// no barriers.
//   Gather: 4 lanes ("quad") per point, lane = 16B chunk of each 64B corner
//     line (16 line-lookups/pt). Wave w gathers points [w*64, w*64+64) of the
//     block; partial feats are redistributed to consumer lanes via
//     ds_bpermute (register-only, wave-local).
//   MLP: per-thread 16->64->3 with weights read via uniform (scalar) loads.

#define NBUCKET (1u << 21)
#define SCAN_BLOCKS 2048   // NBUCKET / 1024

__device__ __forceinline__ int point_key(const float4 xv) {
    // fast binning — performance only, never affects output values
    const float c0 = xv.x * (63.0f / (float)M_PI);
    const float c1 = (xv.y + (float)M_PI) * (63.0f / (float)(2.0 * M_PI));
    const float c2 = (xv.z - (float)(0.5 * M_PI)) * (31.0f / (float)(0.35 * M_PI));
    const float c3 = (xv.w + (float)(0.85 * M_PI)) * (31.0f / (float)(0.35 * M_PI));
    int tx = min(max((int)c0, 0), 63);
    int ty = min(max((int)c1, 0), 63);
    int tz = min(max((int)c2, 0), 31);
    int tw = min(max((int)c3, 0), 31);
    return ((ty * 64 + tx) * 32 + tz) * 16 + (tw >> 1);
}

__global__ __launch_bounds__(256) void k_hist(const float4* __restrict__ x,
                                              unsigned* __restrict__ hist, int N) {
    const int p = blockIdx.x * 256 + threadIdx.x;
    if (p >= N) return;
    atomicAdd(&hist[point_key(x[p])], 1u);
}

__global__ __launch_bounds__(1024) void k_scanA(unsigned* __restrict__ data,
                                                unsigned* __restrict__ partial) {
    __shared__ unsigned s[1024];
    const int t = threadIdx.x;
    const int base = blockIdx.x * 1024;
    const unsigned v = data[base + t];
    s[t] = v;
    __syncthreads();
    #pragma unroll
    for (int off = 1; off < 1024; off <<= 1) {
        const unsigned add = (t >= off) ? s[t - off] : 0u;
        __syncthreads();
        s[t] += add;
        __syncthreads();
    }
    data[base + t] = (t == 0) ? 0u : s[t - 1];           // exclusive
    if (t == 1023) partial[blockIdx.x] = s[1023];
}

__global__ __launch_bounds__(1024) void k_scanB(unsigned* __restrict__ partial) {
    __shared__ unsigned s[1024];
    const int t = threadIdx.x;
    const unsigned v0 = partial[2 * t];
    const unsigned v1 = partial[2 * t + 1];
    s[t] = v0 + v1;
    __syncthreads();
    #pragma unroll
    for (int off = 1; off < 1024; off <<= 1) {
        const unsigned add = (t >= off) ? s[t - off] : 0u;
        __syncthreads();
        s[t] += add;
        __syncthreads();
    }
    const unsigned exc = (t == 0) ? 0u : s[t - 1];
    partial[2 * t] = exc;
    partial[2 * t + 1] = exc + v0;
}

__global__ __launch_bounds__(1024) void k_scanC(unsigned* __restrict__ data,
                                                const unsigned* __restrict__ partial) {
    data[blockIdx.x * 1024 + threadIdx.x] += partial[blockIdx.x];
}

__global__ __launch_bounds__(256) void k_scatter(const float4* __restrict__ x,
                                                 unsigned* __restrict__ offsets,
                                                 float4* __restrict__ xs,
                                                 unsigned* __restrict__ idx, int N) {
    const int p = blockIdx.x * 256 + threadIdx.x;
    if (p >= N) return;
    const float4 xv = x[p];
    const unsigned slot = atomicAdd(&offsets[point_key(xv)], 1u);
    xs[slot] = xv;
    idx[slot] = p;
}

// ---------------- main compute ----------------
template <bool SORTED>
__global__ __launch_bounds__(256, 4) void gridnet_main(
    const float4* __restrict__ xs,
    const unsigned* __restrict__ idx,
    const float* __restrict__ grid,
    const float* __restrict__ w1, const float* __restrict__ b1,
    const float* __restrict__ w2, const float* __restrict__ b2,
    float* __restrict__ out, int N, int nblk)
{
    const int t   = threadIdx.x;
    const int lam = t & 63;        // lane within wave
    const int wv_ = t >> 6;        // wave id (0..3)
    const int ql  = lam >> 2;      // quad within wave (0..15)
    const int l   = lam & 3;       // chunk lane (0..3)
    const int kq  = lam >> 4;      // which gather-iteration this lane consumes

    int b = blockIdx.x;
    if ((nblk & 7) == 0)           // XCD-chunked order
        b = (blockIdx.x & 7) * (nblk >> 3) + (blockIdx.x >> 3);
    const int base = b * 256;

    // BIT-EXACT coordinate constants (f64 python scalars cast to f32)
    const float lo1 = (float)(-M_PI);
    const float sp0 = (float)(M_PI);
    const float sp1 = (float)(2.0 * M_PI);
    const float lo2 = (float)(0.5 * M_PI);
    const float sp2 = (float)(0.85 * M_PI - 0.5 * M_PI);
    const float lo3 = (float)(-0.85 * M_PI);
    const float sp3 = (float)(-0.5 * M_PI - (-0.85 * M_PI));

    // prefetch the 4 query points this quad will process
    float4 xv4[4];
    #pragma unroll
    for (int k = 0; k < 4; ++k) {
        int gp = base + wv_ * 64 + k * 16 + ql;
        if (gp > N - 1) gp = N - 1;
        xv4[k] = xs[gp];
    }

    float feat[16];

    #pragma unroll
    for (int k = 0; k < 4; ++k) {
        const float4 xv = xv4[k];

        // BIT-EXACT: (x - lo) / span * count — divide preserved
        const float c0 = (xv.x - 0.0f) / sp0 * 63.0f;
        const float c1 = (xv.y - lo1) / sp1 * 63.0f;
        const float c2 = (xv.z - lo2) / sp2 * 31.0f;
        const float c3 = (xv.w - lo3) / sp3 * 31.0f;

        const int tlx = (int)c0;
        const int tly = (int)c1;
        const int tlz = (int)c2;
        const int tlw = (int)c3;

        const float xf = c0 - (float)tlx;
        const float yf = c1 - (float)tly;
        const float zf = c2 - (float)tlz;
        const float wf = c3 - (float)tlw;

        const int brx = min(tlx + 1, 63);
        const int bry = min(tly + 1, 63);
        const int brz = min(tlz + 1, 31);
        const int brw = min(tlw + 1, 31);

        const float wx0 = 1.0f - xf, wx1 = xf;
        const float wy0 = 1.0f - yf, wy1 = yf;
        const float wz0 = 1.0f - zf, wz1 = zf;
        const float ww0 = 1.0f - wf, ww1 = wf;

        // reference quirk: iy==1 has (z0,w1)/(z1,w0) swapped
        float cw[2][2][2];
        cw[0][0][0] = wy0 * wz0 * ww0;
        cw[0][0][1] = wy0 * wz0 * ww1;
        cw[0][1][0] = wy0 * wz1 * ww0;
        cw[0][1][1] = wy0 * wz1 * ww1;
        cw[1][0][0] = wy1 * wz0 * ww0;
        cw[1][0][1] = wy1 * wz1 * ww0;   // swapped
        cw[1][1][0] = wy1 * wz0 * ww1;   // swapped
        cw[1][1][1] = wy1 * wz1 * ww1;

        const float wxv[2] = {wx0, wx1};
        const int axv[2] = {tlx, brx};
        const int ayv[2] = {tly, bry};
        const int azv[2] = {tlz, brz};
        const int awv[2] = {tlw, brw};

        float wk[16];
        int   ofs[16];
        #pragma unroll
        for (int iy = 0; iy < 2; ++iy)
          #pragma unroll
          for (int ix = 0; ix < 2; ++ix) {
            const int base1 = (ayv[iy] * 64 + axv[ix]) * 32;
            #pragma unroll
            for (int iz = 0; iz < 2; ++iz) {
              const int base0 = (base1 + azv[iz]) * 32;
              #pragma unroll
              for (int iw = 0; iw < 2; ++iw) {
                const int kk = ((iy * 2 + ix) * 2 + iz) * 2 + iw;
                wk[kk]  = wxv[ix] * cw[iy][iz][iw];
                ofs[kk] = (base0 + awv[iw]) * 64 + l * 16;  // byte offset
              }
            }
          }

        // 16 chunk-loads (each wave instruction consumes 16 full 64B lines)
        float4 cv[16];
        #pragma unroll
        for (int c = 0; c < 16; ++c)
            cv[c] = *reinterpret_cast<const float4*>(
                reinterpret_cast<const char*>(grid) + ofs[c]);

        // bit-exact accumulation chain (corner order 0..15)
        float4 acc = make_float4(0.f, 0.f, 0.f, 0.f);
        #pragma unroll
        for (int c = 0; c < 16; ++c) {
            const float w = wk[c];
            acc.x += w * cv[c].x;
            acc.y += w * cv[c].y;
            acc.z += w * cv[c].z;
            acc.w += w * cv[c].w;
        }

        // redistribute: consumer lane lam (with kq==k) takes chunk c of its
        // point from lane 4*(lam&15)+c  (register-only, wave-local)
        #pragma unroll
        for (int c = 0; c < 4; ++c) {
            const int srcb = (4 * (lam & 15) + c) * 4;
            const float fx = __int_as_float(__builtin_amdgcn_ds_bpermute(srcb, __float_as_int(acc.x)));
            const float fy = __int_as_float(__builtin_amdgcn_ds_bpermute(srcb, __float_as_int(acc.y)));
            const float fz = __int_as_float(__builtin_amdgcn_ds_bpermute(srcb, __float_as_int(acc.z)));
            const float fw = __int_as_float(__builtin_amdgcn_ds_bpermute(srcb, __float_as_int(acc.w)));
            if (kq == k) {
                feat[4 * c + 0] = fx;
                feat[4 * c + 1] = fy;
                feat[4 * c + 2] = fz;
                feat[4 * c + 3] = fw;
            }
        }
    }

    // ---- per-thread MLP; every weight index is uniform -> scalar loads ----
    float o0 = 0.0f, o1 = 0.0f, o2 = 0.0f;
    #pragma unroll
    for (int j4 = 0; j4 < 16; ++j4) {
        float4 h = reinterpret_cast<const float4*>(b1)[j4];
        #pragma unroll
        for (int i = 0; i < 16; ++i) {
            const float4 wvv = reinterpret_cast<const float4*>(w1)[i * 16 + j4];
            h.x += feat[i] * wvv.x;
            h.y += feat[i] * wvv.y;
            h.z += feat[i] * wvv.z;
            h.w += feat[i] * wvv.w;
        }
        const float hx = (h.x >= 0.0f) ? h.x : 0.01f * h.x;
        const float hy = (h.y >= 0.0f) ? h.y : 0.01f * h.y;
        const float hz = (h.z >= 0.0f) ? h.z : 0.01f * h.z;
        const float hw = (h.w >= 0.0f) ? h.w : 0.01f * h.w;
        const float* w2p = w2 + j4 * 12;
        o0 += hx * w2p[0] + hy * w2p[3] + hz * w2p[6] + hw * w2p[9];
        o1 += hx * w2p[1] + hy * w2p[4] + hz * w2p[7] + hw * w2p[10];
        o2 += hx * w2p[2] + hy * w2p[5] + hz * w2p[8] + hw * w2p[11];
    }

    const int gp = base + t;      // consumer point == base + threadIdx.x
    if (gp < N) {
        const int op = SORTED ? (int)idx[gp] : gp;
        float* dst = out + (size_t)op * 3;
        dst[0] = 255.0f / (1.0f + expf(-(o0 + b2[0])));
        dst[1] = 255.0f / (1.0f + expf(-(o1 + b2[1])));
        dst[2] = 255.0f / (1.0f + expf(-(o2 + b2[2])));
    }
}

extern "C" void kernel_launch(void* const* d_in, const int* in_sizes, int n_in,
                              void* d_out, int out_size, void* d_ws, size_t ws_size,
                              hipStream_t stream) {
    const float* x    = (const float*)d_in[0];
    const float* grid = (const float*)d_in[1];
    const float* w1   = (const float*)d_in[2];
    const float* b1   = (const float*)d_in[3];
    const float* w2   = (const float*)d_in[4];
    const float* b2   = (const float*)d_in[5];
    float* out = (float*)d_out;

    const int N = in_sizes[0] / 4;               // x is [N,4]
    const int nblk = (N + 255) / 256;

    const size_t xs_bytes   = (size_t)N * 16;
    const size_t idx_bytes  = (size_t)N * 4;
    const size_t hist_bytes = (size_t)NBUCKET * 4;
    const size_t part_bytes = (size_t)SCAN_BLOCKS * 4;
    const size_t need = xs_bytes + idx_bytes + hist_bytes + part_bytes;

    if (ws_size >= need) {
        char* ws = (char*)d_ws;
        float4*   xs      = (float4*)ws;
        unsigned* idx     = (unsigned*)(ws + xs_bytes);
        unsigned* hist    = (unsigned*)(ws + xs_bytes + idx_bytes);
        unsigned* partial = (unsigned*)(ws + xs_bytes + idx_bytes + hist_bytes);
        const float4* x4 = (const float4*)x;

        hipMemsetAsync(hist, 0, hist_bytes, stream);
        k_hist   <<<nblk, 256, 0, stream>>>(x4, hist, N);
        k_scanA  <<<SCAN_BLOCKS, 1024, 0, stream>>>(hist, partial);
        k_scanB  <<<1, 1024, 0, stream>>>(partial);
        k_scanC  <<<SCAN_BLOCKS, 1024, 0, stream>>>(hist, partial);
        k_scatter<<<nblk, 256, 0, stream>>>(x4, hist, xs, idx, N);
        gridnet_main<true><<<nblk, 256, 0, stream>>>(
            xs, idx, grid, w1, b1, w2, b2, out, N, nblk);
    } else {
        gridnet_main<false><<<nblk, 256, 0, stream>>>(
            (const float4*)x, nullptr, grid, w1, b1, w2, b2, out, N, nblk);
    }
}

// Round 8
// 325.776 us; speedup vs baseline: 1.5682x; 1.5682x over previous
//
#include <hip/hip_runtime.h>
#include <math.h>

// Pipeline: bin points by 4D-Morton cell key (2M buckets) -> process in
// Morton order so each XCD's concurrent block window covers a compact 4D
// brick (~1.5MB corner working set -> L2-resident reuse).
// Main kernel (= round-6 structure): 256 threads / 256 points per block.
//   Phase 1 (gather): 4 lanes per point, lane = 16B chunk of each 64B corner
//     line -> every wave load instruction consumes 16 full cache lines.
//   Phase 2 (MLP GEMM): thread = (8-point group, 8-j group) tile; h[8][8] in
//     regs; o reduced across j-groups via in-wave shfl_xor butterfly.

#define NBUCKET (1u << 21)
#define SCAN_BLOCKS 2048        // NBUCKET / 1024
#define FEAT_PITCH 260          // 16B-aligned rows, bank-stagger

__device__ __forceinline__ unsigned morton_key(int ty, int tx, int tz, int tw2) {
    // ty,tx: 6b; tz: 5b; tw2: 4b -> 21-bit Morton, LSB-first (w,z,x,y)
    unsigned k = 0;
    int pos = 0;
    #pragma unroll
    for (int b = 0; b < 6; ++b) {
        if (b < 4) { k |= ((unsigned)((tw2 >> b) & 1)) << pos; ++pos; }
        if (b < 5) { k |= ((unsigned)((tz  >> b) & 1)) << pos; ++pos; }
        k |= ((unsigned)((tx >> b) & 1)) << pos; ++pos;
        k |= ((unsigned)((ty >> b) & 1)) << pos; ++pos;
    }
    return k;
}

__device__ __forceinline__ unsigned point_key(const float4 xv) {
    // fast binning — performance only, never affects output values
    const float c0 = xv.x * (63.0f / (float)M_PI);
    const float c1 = (xv.y + (float)M_PI) * (63.0f / (float)(2.0 * M_PI));
    const float c2 = (xv.z - (float)(0.5 * M_PI)) * (31.0f / (float)(0.35 * M_PI));
    const float c3 = (xv.w + (float)(0.85 * M_PI)) * (31.0f / (float)(0.35 * M_PI));
    int tx = min(max((int)c0, 0), 63);
    int ty = min(max((int)c1, 0), 63);
    int tz = min(max((int)c2, 0), 31);
    int tw = min(max((int)c3, 0), 31);
    return morton_key(ty, tx, tz, tw >> 1);
}

__global__ __launch_bounds__(256) void k_hist(const float4* __restrict__ x,
                                              unsigned* __restrict__ hist, int N) {
    const int p = blockIdx.x * 256 + threadIdx.x;
    if (p >= N) return;
    atomicAdd(&hist[point_key(x[p])], 1u);
}

__global__ __launch_bounds__(1024) void k_scanA(unsigned* __restrict__ data,
                                                unsigned* __restrict__ partial) {
    __shared__ unsigned s[1024];
    const int t = threadIdx.x;
    const int base = blockIdx.x * 1024;
    const unsigned v = data[base + t];
    s[t] = v;
    __syncthreads();
    #pragma unroll
    for (int off = 1; off < 1024; off <<= 1) {
        const unsigned add = (t >= off) ? s[t - off] : 0u;
        __syncthreads();
        s[t] += add;
        __syncthreads();
    }
    data[base + t] = (t == 0) ? 0u : s[t - 1];           // exclusive
    if (t == 1023) partial[blockIdx.x] = s[1023];
}

__global__ __launch_bounds__(1024) void k_scanB(unsigned* __restrict__ partial) {
    __shared__ unsigned s[1024];
    const int t = threadIdx.x;
    const unsigned v0 = partial[2 * t];
    const unsigned v1 = partial[2 * t + 1];
    s[t] = v0 + v1;
    __syncthreads();
    #pragma unroll
    for (int off = 1; off < 1024; off <<= 1) {
        const unsigned add = (t >= off) ? s[t - off] : 0u;
        __syncthreads();
        s[t] += add;
        __syncthreads();
    }
    const unsigned exc = (t == 0) ? 0u : s[t - 1];
    partial[2 * t] = exc;
    partial[2 * t + 1] = exc + v0;
}

__global__ __launch_bounds__(1024) void k_scanC(unsigned* __restrict__ data,
                                                const unsigned* __restrict__ partial) {
    data[blockIdx.x * 1024 + threadIdx.x] += partial[blockIdx.x];
}

__global__ __launch_bounds__(256) void k_scatter(const float4* __restrict__ x,
                                                 unsigned* __restrict__ offsets,
                                                 float4* __restrict__ xs,
                                                 unsigned* __restrict__ idx, int N) {
    const int p = blockIdx.x * 256 + threadIdx.x;
    if (p >= N) return;
    const float4 xv = x[p];
    const unsigned slot = atomicAdd(&offsets[point_key(xv)], 1u);
    xs[slot] = xv;
    idx[slot] = p;
}

// ---------------- main compute (round-6 structure, bit-exact) ----------------
template <bool SORTED>
__global__ __launch_bounds__(256, 4) void gridnet_main(
    const float4* __restrict__ xs,
    const unsigned* __restrict__ idx,
    const float* __restrict__ grid,
    const float* __restrict__ w1, const float* __restrict__ b1,
    const float* __restrict__ w2, const float* __restrict__ b2,
    float* __restrict__ out, int N, int nblk)
{
    __shared__ float w1s[1024];                 // [16][64]
    __shared__ float featS[16 * FEAT_PITCH];    // [i][pt]
    __shared__ float b1s[64];
    __shared__ float w2s[192];                  // [64][3]
    __shared__ float b2s[4];

    const int t = threadIdx.x;
    for (int i = t; i < 1024; i += 256) w1s[i] = w1[i];
    if (t < 64)  b1s[t] = b1[t];
    if (t < 192) w2s[t] = w2[t];
    if (t < 3)   b2s[t] = b2[t];

    int b = blockIdx.x;
    if ((nblk & 7) == 0)                        // XCD-chunked order
        b = (blockIdx.x & 7) * (nblk >> 3) + (blockIdx.x >> 3);
    const int base = b * 256;

    // BIT-EXACT coordinate constants (f64 python scalars cast to f32)
    const float lo1 = (float)(-M_PI);
    const float sp0 = (float)(M_PI);
    const float sp1 = (float)(2.0 * M_PI);
    const float lo2 = (float)(0.5 * M_PI);
    const float sp2 = (float)(0.85 * M_PI - 0.5 * M_PI);
    const float lo3 = (float)(-0.85 * M_PI);
    const float sp3 = (float)(-0.5 * M_PI - (-0.85 * M_PI));

    // ---- phase 1: gather. quad qb = t>>2 handles pts qb+64k, lane = chunk.
    const int l  = t & 3;
    const int qb = t >> 2;

    #pragma unroll
    for (int k = 0; k < 4; ++k) {
        const int pl = qb + 64 * k;            // local point
        const int gp = base + pl;
        float4 acc = make_float4(0.f, 0.f, 0.f, 0.f);
        if (gp < N) {
            const float4 xv = xs[gp];

            const float c0 = (xv.x - 0.0f) / sp0 * 63.0f;
            const float c1 = (xv.y - lo1) / sp1 * 63.0f;
            const float c2 = (xv.z - lo2) / sp2 * 31.0f;
            const float c3 = (xv.w - lo3) / sp3 * 31.0f;

            const int tlx = (int)c0;
            const int tly = (int)c1;
            const int tlz = (int)c2;
            const int tlw = (int)c3;

            const float xf = c0 - (float)tlx;
            const float yf = c1 - (float)tly;
            const float zf = c2 - (float)tlz;
            const float wf = c3 - (float)tlw;

            const int brx = min(tlx + 1, 63);
            const int bry = min(tly + 1, 63);
            const int brz = min(tlz + 1, 31);
            const int brw = min(tlw + 1, 31);

            const float wx0 = 1.0f - xf, wx1 = xf;
            const float wy0 = 1.0f - yf, wy1 = yf;
            const float wz0 = 1.0f - zf, wz1 = zf;
            const float ww0 = 1.0f - wf, ww1 = wf;

            // reference quirk: iy==1 has (z0,w1)/(z1,w0) swapped
            float cw[2][2][2];
            cw[0][0][0] = wy0 * wz0 * ww0;
            cw[0][0][1] = wy0 * wz0 * ww1;
            cw[0][1][0] = wy0 * wz1 * ww0;
            cw[0][1][1] = wy0 * wz1 * ww1;
            cw[1][0][0] = wy1 * wz0 * ww0;
            cw[1][0][1] = wy1 * wz1 * ww0;   // swapped
            cw[1][1][0] = wy1 * wz0 * ww1;   // swapped
            cw[1][1][1] = wy1 * wz1 * ww1;

            const float wxv[2] = {wx0, wx1};
            const int axv[2] = {tlx, brx};
            const int ayv[2] = {tly, bry};
            const int azv[2] = {tlz, brz};
            const int awv[2] = {tlw, brw};

            float wk[16];
            int   ofs[16];
            #pragma unroll
            for (int iy = 0; iy < 2; ++iy)
              #pragma unroll
              for (int ix = 0; ix < 2; ++ix) {
                const int base1 = (ayv[iy] * 64 + axv[ix]) * 32;
                #pragma unroll
                for (int iz = 0; iz < 2; ++iz) {
                  const int base0 = (base1 + azv[iz]) * 32;
                  #pragma unroll
                  for (int iw = 0; iw < 2; ++iw) {
                    const int kk = ((iy * 2 + ix) * 2 + iz) * 2 + iw;
                    wk[kk]  = wxv[ix] * cw[iy][iz][iw];
                    ofs[kk] = (base0 + awv[iw]) * 64 + l * 16;  // byte offset
                  }
                }
              }

            #pragma unroll
            for (int h8 = 0; h8 < 2; ++h8) {
                float4 cv[8];
                #pragma unroll
                for (int c = 0; c < 8; ++c)
                    cv[c] = *reinterpret_cast<const float4*>(
                        reinterpret_cast<const char*>(grid) + ofs[h8 * 8 + c]);
                #pragma unroll
                for (int c = 0; c < 8; ++c) {
                    const float w = wk[h8 * 8 + c];
                    acc.x += w * cv[c].x;
                    acc.y += w * cv[c].y;
                    acc.z += w * cv[c].z;
                    acc.w += w * cv[c].w;
                }
            }
        }
        featS[(4 * l + 0) * FEAT_PITCH + pl] = acc.x;
        featS[(4 * l + 1) * FEAT_PITCH + pl] = acc.y;
        featS[(4 * l + 2) * FEAT_PITCH + pl] = acc.z;
        featS[(4 * l + 3) * FEAT_PITCH + pl] = acc.w;
    }
    __syncthreads();

    // ---- phase 2: MLP GEMM. thread = (pg: 8 pts, g: 8 js)
    const int g  = t & 7;
    const int pg = t >> 3;

    float h[8][8];
    #pragma unroll
    for (int p = 0; p < 8; ++p)
        #pragma unroll
        for (int j = 0; j < 8; ++j)
            h[p][j] = b1s[g * 8 + j];

    #pragma unroll
    for (int i = 0; i < 16; ++i) {
        const float4 wA = *reinterpret_cast<const float4*>(&w1s[i * 64 + g * 8]);
        const float4 wB = *reinterpret_cast<const float4*>(&w1s[i * 64 + g * 8 + 4]);
        const float4 fA = *reinterpret_cast<const float4*>(&featS[i * FEAT_PITCH + pg * 8]);
        const float4 fB = *reinterpret_cast<const float4*>(&featS[i * FEAT_PITCH + pg * 8 + 4]);
        const float fv[8] = {fA.x, fA.y, fA.z, fA.w, fB.x, fB.y, fB.z, fB.w};
        const float wv[8] = {wA.x, wA.y, wA.z, wA.w, wB.x, wB.y, wB.z, wB.w};
        #pragma unroll
        for (int p = 0; p < 8; ++p)
            #pragma unroll
            for (int j = 0; j < 8; ++j)
                h[p][j] += fv[p] * wv[j];
    }

    float o[8][3];
    #pragma unroll
    for (int p = 0; p < 8; ++p) { o[p][0] = 0.f; o[p][1] = 0.f; o[p][2] = 0.f; }

    #pragma unroll
    for (int j = 0; j < 8; ++j) {
        const float w20 = w2s[(g * 8 + j) * 3 + 0];
        const float w21 = w2s[(g * 8 + j) * 3 + 1];
        const float w22 = w2s[(g * 8 + j) * 3 + 2];
        #pragma unroll
        for (int p = 0; p < 8; ++p) {
            const float hv = (h[p][j] >= 0.0f) ? h[p][j] : 0.01f * h[p][j];
            o[p][0] += hv * w20;
            o[p][1] += hv * w21;
            o[p][2] += hv * w22;
        }
    }

    #pragma unroll
    for (int m = 1; m < 8; m <<= 1)
        #pragma unroll
        for (int p = 0; p < 8; ++p) {
            o[p][0] += __shfl_xor(o[p][0], m);
            o[p][1] += __shfl_xor(o[p][1], m);
            o[p][2] += __shfl_xor(o[p][2], m);
        }

    float og[3];
    #pragma unroll
    for (int p = 0; p < 8; ++p)
        if (p == g) { og[0] = o[p][0]; og[1] = o[p][1]; og[2] = o[p][2]; }

    const int pl = pg * 8 + g;
    const int gp = base + pl;
    if (gp < N) {
        const int op = SORTED ? (int)idx[gp] : gp;
        float* dst = out + (size_t)op * 3;
        #pragma unroll
        for (int c = 0; c < 3; ++c) {
            const float v = og[c] + b2s[c];
            dst[c] = 255.0f / (1.0f + expf(-v));
        }
    }
}

extern "C" void kernel_launch(void* const* d_in, const int* in_sizes, int n_in,
                              void* d_out, int out_size, void* d_ws, size_t ws_size,
                              hipStream_t stream) {
    const float* x    = (const float*)d_in[0];
    const float* grid = (const float*)d_in[1];
    const float* w1   = (const float*)d_in[2];
    const float* b1   = (const float*)d_in[3];
    const float* w2   = (const float*)d_in[4];
    const float* b2   = (const float*)d_in[5];
    float* out = (float*)d_out;

    const int N = in_sizes[0] / 4;               // x is [N,4]
    const int nblk = (N + 255) / 256;

    const size_t xs_bytes   = (size_t)N * 16;
    const size_t idx_bytes  = (size_t)N * 4;
    const size_t hist_bytes = (size_t)NBUCKET * 4;
    const size_t part_bytes = (size_t)SCAN_BLOCKS * 4;
    const size_t need = xs_bytes + idx_bytes + hist_bytes + part_bytes;

    if (ws_size >= need) {
        char* ws = (char*)d_ws;
        float4*   xs      = (float4*)ws;
        unsigned* idx     = (unsigned*)(ws + xs_bytes);
        unsigned* hist    = (unsigned*)(ws + xs_bytes + idx_bytes);
        unsigned* partial = (unsigned*)(ws + xs_bytes + idx_bytes + hist_bytes);
        const float4* x4 = (const float4*)x;

        hipMemsetAsync(hist, 0, hist_bytes, stream);
        k_hist   <<<nblk, 256, 0, stream>>>(x4, hist, N);
        k_scanA  <<<SCAN_BLOCKS, 1024, 0, stream>>>(hist, partial);
        k_scanB  <<<1, 1024, 0, stream>>>(partial);
        k_scanC  <<<SCAN_BLOCKS, 1024, 0, stream>>>(hist, partial);
        k_scatter<<<nblk, 256, 0, stream>>>(x4, hist, xs, idx, N);
        gridnet_main<true><<<nblk, 256, 0, stream>>>(
            xs, idx, grid, w1, b1, w2, b2, out, N, nblk);
    } else {
        gridnet_main<false><<<nblk, 256, 0, stream>>>(
            (const float4*)x, nullptr, grid, w1, b1, w2, b2, out, N, nblk);
    }
}